// Round 12
// baseline (62.094 us; speedup 1.0000x reference)
//
#include <hip/hip_runtime.h>
#include <math.h>

#define BS 4
#define LQ 128
#define IMG 256
#define NPIX (IMG*IMG)
#define NCELL 4096
#define CAPC 24
#define OCAP 8192
#define CELLW 0.0625f
#define NBLKQ (BS*LQ)        // 512 query blocks

// ws byte offsets
#define WS_COUNTER 0
#define WS_OCNT    64
#define WS_WSQ     4096      // float2[512][8] = 32 KB
#define WS_GCNT    65536     // u32[4][4096]   = 64 KB
#define WS_OVER    131072    // float4[4][8192] = 512 KB
#define WS_CELLS   1048576   // float4[4][4096][24] = 6 MB

__device__ __forceinline__ bool lessVI(float v1, int i1, float v2, int i2) {
    return (v1 < v2) || (v1 == v2 && i1 < i2);
}

#define CE8(WV, WI, a, c)                                                     \
    do {                                                                      \
        if (lessVI((WV)[c], (WI)[c], (WV)[a], (WI)[a])) {                     \
            float tv_ = (WV)[a]; (WV)[a] = (WV)[c]; (WV)[c] = tv_;            \
            int   ti_ = (WI)[a]; (WI)[a] = (WI)[c]; (WI)[c] = ti_;            \
        }                                                                     \
    } while (0)

#define MERGE8(AV, AI, BV, BI, OV, OI)                                        \
    do {                                                                      \
        _Pragma("unroll")                                                     \
        for (int k_ = 0; k_ < 8; ++k_) {                                      \
            if (lessVI((AV)[k_], (AI)[k_], (BV)[7-k_], (BI)[7-k_])) {         \
                (OV)[k_] = (AV)[k_]; (OI)[k_] = (AI)[k_];                     \
            } else { (OV)[k_] = (BV)[7-k_]; (OI)[k_] = (BI)[7-k_]; }          \
        }                                                                     \
        CE8(OV, OI, 0, 4); CE8(OV, OI, 1, 5); CE8(OV, OI, 2, 6); CE8(OV, OI, 3, 7); \
        CE8(OV, OI, 0, 2); CE8(OV, OI, 1, 3); CE8(OV, OI, 4, 6); CE8(OV, OI, 5, 7); \
        CE8(OV, OI, 0, 1); CE8(OV, OI, 2, 3); CE8(OV, OI, 4, 5); CE8(OV, OI, 6, 7); \
    } while (0)

__device__ __forceinline__ int cell_of(float r, float g, float b) {
    // *16 is exact (exponent shift); (int) is floor for nonneg => exact cell
    const int cx = min((int)(r * 16.0f), 15);
    const int cy = min((int)(g * 16.0f), 15);
    const int cz = min((int)(b * 16.0f), 15);
    return cx | (cy << 4) | (cz << 8);
}

// zero the ticket counter, ocnt, and gcnt (the hipMemsetAsync fill path
// costs ~39 us fixed regardless of size -- a plain kernel is ~2-3 us)
__global__ __launch_bounds__(256)
void zero_kernel(int* __restrict__ head, unsigned* __restrict__ gcnt) {
    const int g = blockIdx.x * 256 + threadIdx.x;   // 64 blocks -> 16384 thr
    gcnt[g] = 0u;                                   // 64 KB
    if (g < 32) head[g] = 0;                        // counter + ocnt region
}

// 64 blocks (batch b = bid>>4, chunk = bid&15) x 256 threads.
// Counting-scatter 4096 px/chunk into per-(batch,cell) arrays (cap 24) with
// exact fp32 colors; beyond-cap pixels go to a per-batch overflow list.
__global__ __launch_bounds__(256)
void build_kernel(const float* __restrict__ imgs,
                  unsigned* __restrict__ gcnt,
                  float4* __restrict__ cells,
                  float4* __restrict__ overflow,
                  int* __restrict__ ocnt) {
    __shared__ unsigned lhist[NCELL];
    __shared__ unsigned lbase[NCELL];
    const int bid = blockIdx.x;
    const int b = bid >> 4;
    const int chunk = bid & 15;
    const int tid = threadIdx.x;
    const float* img = imgs + b * 3 * NPIX;
    const float4* i0 = (const float4*)img;
    const float4* i1 = (const float4*)(img + NPIX);
    const float4* i2 = (const float4*)(img + 2 * NPIX);

#pragma unroll
    for (int k = 0; k < NCELL / 256; ++k) lhist[tid + k * 256] = 0;
    __syncthreads();

    // phase 1: local histogram
#pragma unroll
    for (int i = 0; i < 4; ++i) {
        const int idx4 = chunk * 1024 + i * 256 + tid;
        const float4 r = i0[idx4];
        const float4 g = i1[idx4];
        const float4 bl = i2[idx4];
        atomicAdd(&lhist[cell_of(r.x, g.x, bl.x)], 1u);
        atomicAdd(&lhist[cell_of(r.y, g.y, bl.y)], 1u);
        atomicAdd(&lhist[cell_of(r.z, g.z, bl.z)], 1u);
        atomicAdd(&lhist[cell_of(r.w, g.w, bl.w)], 1u);
    }
    __syncthreads();

    // phase 2: reserve global ranges per nonzero cell; reset cursors
#pragma unroll
    for (int k = 0; k < NCELL / 256; ++k) {
        const int c = tid + k * 256;
        const unsigned h = lhist[c];
        lbase[c] = h ? atomicAdd(&gcnt[b * NCELL + c], h) : 0u;
    }
    __syncthreads();
#pragma unroll
    for (int k = 0; k < NCELL / 256; ++k) lhist[tid + k * 256] = 0;
    __syncthreads();

    // phase 3: scatter (cell arrays unordered -> fine, selection is
    // order-invariant lexicographic (val,idx))
#pragma unroll
    for (int i = 0; i < 4; ++i) {
        const int idx4 = chunk * 1024 + i * 256 + tid;
        const float4 r = i0[idx4];
        const float4 g = i1[idx4];
        const float4 bl = i2[idx4];
        const int pbase = idx4 * 4;
#define SCAT(RR, GG, BB, J)                                                   \
        do {                                                                  \
            const int c_ = cell_of(RR, GG, BB);                               \
            const unsigned lo_ = atomicAdd(&lhist[c_], 1u);                   \
            const unsigned slot_ = lbase[c_] + lo_;                           \
            float4 e_; e_.x = (RR); e_.y = (GG); e_.z = (BB);                 \
            e_.w = __int_as_float(pbase + (J));                               \
            if (slot_ < CAPC) {                                               \
                cells[(b * NCELL + c_) * CAPC + slot_] = e_;                  \
            } else {                                                          \
                const int o_ = atomicAdd(&ocnt[b], 1);                        \
                if (o_ < OCAP) overflow[b * OCAP + o_] = e_;                  \
            }                                                                 \
        } while (0)
        SCAT(r.x, g.x, bl.x, 0);
        SCAT(r.y, g.y, bl.y, 1);
        SCAT(r.z, g.z, bl.z, 2);
        SCAT(r.w, g.w, bl.w, 3);
#undef SCAT
    }
}

#define INSERT(SIM, PIX)                                                      \
    do {                                                                      \
        if (lessVI((SIM), (PIX), bv[7], bi[7])) {                             \
            bv[7] = (SIM); bi[7] = (PIX);                                     \
            _Pragma("unroll")                                                 \
            for (int k = 7; k > 0; --k) {                                     \
                if (lessVI(bv[k], bi[k], bv[k - 1], bi[k - 1])) {             \
                    float tv = bv[k]; bv[k] = bv[k - 1]; bv[k - 1] = tv;      \
                    int   ti = bi[k]; bi[k] = bi[k - 1]; bi[k - 1] = ti;      \
                }                                                             \
            }                                                                 \
        }                                                                     \
    } while (0)

#define WAVE_BITONIC()                                                        \
    do {                                                                      \
        _Pragma("unroll")                                                     \
        for (int off = 1; off < 64; off <<= 1) {                              \
            float ov[8]; int oi[8];                                           \
            _Pragma("unroll")                                                 \
            for (int k = 0; k < 8; ++k) {                                     \
                ov[k] = __shfl_xor(bv[k], off, 64);                           \
                oi[k] = __shfl_xor(bi[k], off, 64);                           \
            }                                                                 \
            float w[8]; int wi[8];                                            \
            _Pragma("unroll")                                                 \
            for (int k = 0; k < 8; ++k) {                                     \
                if (lessVI(bv[k], bi[k], ov[7 - k], oi[7 - k])) {             \
                    w[k] = bv[k]; wi[k] = bi[k];                              \
                } else { w[k] = ov[7 - k]; wi[k] = oi[7 - k]; }               \
            }                                                                 \
            CE8(w, wi, 0, 4); CE8(w, wi, 1, 5); CE8(w, wi, 2, 6); CE8(w, wi, 3, 7); \
            CE8(w, wi, 0, 2); CE8(w, wi, 1, 3); CE8(w, wi, 4, 6); CE8(w, wi, 5, 7); \
            CE8(w, wi, 0, 1); CE8(w, wi, 2, 3); CE8(w, wi, 4, 5); CE8(w, wi, 6, 7); \
            _Pragma("unroll")                                                 \
            for (int k = 0; k < 8; ++k) { bv[k] = w[k]; bi[k] = wi[k]; }      \
        }                                                                     \
    } while (0)

// 512 blocks x 256 threads: one block per query (b,l).
// Stage 1: exact scan of the 27-cell box around pooled color; per-lane lists
//          stay DISJOINT (bound S8 computed on a values-only copy).
// Stage 2: scan remaining cells with d_min <= S8 (usually none) + overflow.
// One final wave bitonic + cross-wave merge -> exact lexicographic top-8.
// Ticket: last block computes the loss.
__global__ __launch_bounds__(256)
void query_kernel(const float* __restrict__ pred,
                  const float* __restrict__ imgs,
                  const unsigned* __restrict__ gcnt,
                  const float4* __restrict__ cells,
                  const float4* __restrict__ overflow,
                  const int* __restrict__ ocnt,
                  float2* __restrict__ wsq,
                  int* __restrict__ counter,
                  float* __restrict__ out) {
    __shared__ float mvv[4][8];
    __shared__ int   mii[4][8];
    __shared__ float tau4[4];
    __shared__ int   lastflag;
    __shared__ float red[256];

    const int qid = blockIdx.x;
    const int b = qid >> 7;
    const int l = qid & (LQ - 1);
    const int tid = threadIdx.x;
    const int wid = tid >> 6;
    const int lane = tid & 63;

    // pooled color (reshape quirk: flat row n = l*BS + b of preds(bs*L,2))
    const int n  = l * BS + b;
    const int pb = n >> 7;
    const int pl = n & (LQ - 1);
    const float gx = pred[(pb * LQ + pl) * 8 + 0];
    const float gy = pred[(pb * LQ + pl) * 8 + 1];
    const int ix = (int)fminf(fmaxf(rintf(gx * 256.0f - 0.5f), 0.0f), 255.0f);
    const int iy = (int)fminf(fmaxf(rintf(gy * 256.0f - 0.5f), 0.0f), 255.0f);
    const float* img = imgs + b * 3 * NPIX;
    const int pc = iy * IMG + ix;
    const float c0 = img[pc];
    const float c1 = img[NPIX + pc];
    const float c2 = img[2 * NPIX + pc];
    const int qx = min((int)(c0 * 16.0f), 15);
    const int qy = min((int)(c1 * 16.0f), 15);
    const int qz = min((int)(c2 * 16.0f), 15);

    const unsigned* cnt_b = gcnt + b * NCELL;
    const float4*   cel_b = cells + b * NCELL * CAPC;

    float bv[8]; int bi[8];
#pragma unroll
    for (int k = 0; k < 8; ++k) { bv[k] = 3.0e38f; bi[k] = 0x7FFFFFFF; }

    // ---- Stage 1: 27-cell box, 9 threads per cell (per-lane disjoint)
    if (tid < 243) {
        const int ci = tid / 9;
        const int sub = tid % 9;
        const int cx = qx + (ci % 3) - 1;
        const int cy = qy + ((ci / 3) % 3) - 1;
        const int cz = qz + (ci / 9) - 1;
        if (cx >= 0 && cx < 16 && cy >= 0 && cy < 16 && cz >= 0 && cz < 16) {
            const int c = cx | (cy << 4) | (cz << 8);
            const int ce = min((int)cnt_b[c], CAPC);
            for (int e = sub; e < ce; e += 9) {
                const float4 E = cel_b[c * CAPC + e];
                const float sim = fabsf(E.x - c0) + fabsf(E.y - c1) + fabsf(E.z - c2);
                INSERT(sim, __float_as_int(E.w));
            }
        }
    }
    // S8 bound from a VALUES-ONLY copy (keeps bv/bi per-lane disjoint!)
    {
        float tv[8];
#pragma unroll
        for (int k = 0; k < 8; ++k) tv[k] = bv[k];
#pragma unroll
        for (int off = 1; off < 64; off <<= 1) {
            float ov[8];
#pragma unroll
            for (int k = 0; k < 8; ++k) ov[k] = __shfl_xor(tv[k], off, 64);
            float w[8];
#pragma unroll
            for (int k = 0; k < 8; ++k) w[k] = fminf(tv[k], ov[7 - k]);
#define CEW(a, c) do { float lo = fminf(w[a], w[c]); float hi = fmaxf(w[a], w[c]); w[a] = lo; w[c] = hi; } while (0)
            CEW(0, 4); CEW(1, 5); CEW(2, 6); CEW(3, 7);
            CEW(0, 2); CEW(1, 3); CEW(4, 6); CEW(5, 7);
            CEW(0, 1); CEW(2, 3); CEW(4, 5); CEW(6, 7);
#undef CEW
#pragma unroll
            for (int k = 0; k < 8; ++k) tv[k] = w[k];
        }
        if (lane == 0) tau4[wid] = tv[7];   // wave's 8th smallest (or 3e38)
    }
    __syncthreads();
    // each wave-8th is an upper bound on the block's true 8th (>=8 elems <=
    // it); min over waves = tightest available valid bound
    const float S8 = fminf(fminf(tau4[0], tau4[1]), fminf(tau4[2], tau4[3]));

    // ---- Stage 2: cells with d_min <= S8 outside the 27-box, + overflow
    {
        const int R = (S8 > 1.0f) ? 16 : min((int)(S8 * 16.0f) + 2, 16);
        const int side = 2 * R + 1;
        const int tot = side * side * side;
        for (int t2 = tid; t2 < tot; t2 += 256) {
            const int dx = t2 % side - R;
            const int dy = (t2 / side) % side - R;
            const int dz = t2 / (side * side) - R;
            if (dx >= -1 && dx <= 1 && dy >= -1 && dy <= 1 && dz >= -1 && dz <= 1)
                continue;   // already scanned in stage 1
            const int cx = qx + dx, cy = qy + dy, cz = qz + dz;
            if (cx < 0 || cx > 15 || cy < 0 || cy > 15 || cz < 0 || cz > 15)
                continue;
            // conservative fp32 lower bound on any pixel's sim in this cell
            const float lox = cx * CELLW, loy = cy * CELLW, loz = cz * CELLW;
            const float dmx = fmaxf(fmaxf(lox - c0, c0 - (lox + CELLW)), 0.0f);
            const float dmy = fmaxf(fmaxf(loy - c1, c1 - (loy + CELLW)), 0.0f);
            const float dmz = fmaxf(fmaxf(loz - c2, c2 - (loz + CELLW)), 0.0f);
            if (dmx + dmy + dmz > S8) continue;
            const int c = cx | (cy << 4) | (cz << 8);
            const int ce = min((int)cnt_b[c], CAPC);
            for (int e = 0; e < ce; ++e) {
                const float4 E = cel_b[c * CAPC + e];
                const float sim = fabsf(E.x - c0) + fabsf(E.y - c1) + fabsf(E.z - c2);
                INSERT(sim, __float_as_int(E.w));
            }
        }
        const int oc = min(ocnt[b], OCAP);
        for (int e = tid; e < oc; e += 256) {
            const float4 E = overflow[b * OCAP + e];
            const float sim = fabsf(E.x - c0) + fabsf(E.y - c1) + fabsf(E.z - c2);
            INSERT(sim, __float_as_int(E.w));
        }
    }

    // ---- single final reduction: wave bitonic + cross-wave merge
    WAVE_BITONIC();
    if (lane == 0) {
#pragma unroll
        for (int k = 0; k < 8; ++k) { mvv[wid][k] = bv[k]; mii[wid][k] = bi[k]; }
    }
    __syncthreads();
    if (tid == 0) {
        float a0[8], a1[8], a2[8], a3[8], m0[8], m1[8], f[8];
        int   x0[8], x1[8], x2[8], x3[8], y0[8], y1[8], z[8];
#pragma unroll
        for (int k = 0; k < 8; ++k) {
            a0[k] = mvv[0][k]; x0[k] = mii[0][k];
            a1[k] = mvv[1][k]; x1[k] = mii[1][k];
            a2[k] = mvv[2][k]; x2[k] = mii[2][k];
            a3[k] = mvv[3][k]; x3[k] = mii[3][k];
        }
        MERGE8(a0, x0, a1, x1, m0, y0);
        MERGE8(a2, x2, a3, x3, m1, y1);
        MERGE8(m0, y0, m1, y1, f, z);
        float2* o = wsq + qid * 8;
#pragma unroll
        for (int k = 0; k < 8; ++k) {
            float2 e; e.x = f[k]; e.y = __int_as_float(z[k]);
            o[k] = e;
        }
    }
    __syncthreads();

    // ---- device-scope ticket: last arrival computes the loss
    if (tid == 0) {
        __threadfence();
        const int t = atomicAdd(counter, 1);
        lastflag = ((t % NBLKQ) == (NBLKQ - 1)) ? 1 : 0;
    }
    __syncthreads();
    if (!lastflag) return;
    __threadfence();

    {
        float acc = 0.0f;
#pragma unroll
        for (int pp = 0; pp < 2; ++pp) {
            const int p = tid + pp * 256;
            const int b2 = p >> 7;
            const int l2 = p & (LQ - 1);
            if (l2 >= 1) {
                const int mq = b2 * LQ + (l2 - 1);
                const float2* base = wsq + mq * 8;
                const float qx2 = pred[(b2 * LQ + l2) * 8 + 0];
                const float qy2 = pred[(b2 * LQ + l2) * 8 + 1];
                float best = 3.0e38f;
#pragma unroll
                for (int k = 0; k < 8; ++k) {
                    const float2 e = base[k];
                    const int id = __float_as_int(e.y);
                    const float tx = (float)(id & (IMG - 1)) * (1.0f / IMG);
                    const float ty = (float)(id >> 8)        * (1.0f / IMG);
                    const float dx = qx2 - tx;
                    const float dy = qy2 - ty;
                    best = fminf(best, sqrtf(dx * dx + dy * dy));
                }
                acc += best;
            }
        }
        red[tid] = acc;
        __syncthreads();
        for (int s = 128; s > 0; s >>= 1) {
            if (tid < s) red[tid] += red[tid + s];
            __syncthreads();
        }
        if (tid == 0) out[0] = red[0] * (1.0f / (BS * (LQ - 1)));
    }
}

extern "C" void kernel_launch(void* const* d_in, const int* in_sizes, int n_in,
                              void* d_out, int out_size, void* d_ws, size_t ws_size,
                              hipStream_t stream) {
    const float* pred = (const float*)d_in[0];   // (4,128,8) f32
    const float* imgs = (const float*)d_in[1];   // (4,3,256,256) f32
    float* out = (float*)d_out;                  // scalar f32

    char* w = (char*)d_ws;
    int*      head     = (int*)(w + WS_COUNTER);   // counter @0, ocnt @64
    int*      counter  = (int*)(w + WS_COUNTER);
    int*      ocnt     = (int*)(w + WS_OCNT);
    float2*   wsq      = (float2*)(w + WS_WSQ);
    unsigned* gcnt     = (unsigned*)(w + WS_GCNT);
    float4*   overflow = (float4*)(w + WS_OVER);
    float4*   cells    = (float4*)(w + WS_CELLS);

    hipLaunchKernelGGL(zero_kernel, dim3(64), dim3(256), 0, stream,
                       head, gcnt);
    hipLaunchKernelGGL(build_kernel, dim3(64), dim3(256), 0, stream,
                       imgs, gcnt, cells, overflow, ocnt);
    hipLaunchKernelGGL(query_kernel, dim3(NBLKQ), dim3(256), 0, stream,
                       pred, imgs, gcnt, cells, overflow, ocnt,
                       wsq, counter, out);
}